// Round 5
// baseline (439.862 us; speedup 1.0000x reference)
//
#include <hip/hip_runtime.h>

#define B 8
#define P 2048
#define C 1024
#define NCHUNK 32
#define FEAT4 (B*P*C/4)   // 4194304 float4s of features
#define CEN4  (B*P*3/4)   // 12288 float4s of centers (and of cls_preds)

typedef unsigned long long u64;
typedef unsigned int u32;

__device__ __forceinline__ u64 shfl_xor_u64(u64 x, int m) {
    int lo = __shfl_xor((int)(u32)x, m, 64);
    int hi = __shfl_xor((int)(u32)(x >> 32), m, 64);
    return ((u64)(u32)hi << 32) | (u32)lo;
}
__device__ __forceinline__ u64 shfl_u64(u64 x, int s) {
    int lo = __shfl((int)(u32)x, s, 64);
    int hi = __shfl((int)(u32)(x >> 32), s, 64);
    return ((u64)(u32)hi << 32) | (u32)lo;
}

// ---------------------------------------------------------------------------
// Fused sort + greedy NMS. One block (16 waves) per scene.
//
// Phase 1: hybrid bitonic sort of packed keys (desc score | idx<<2 | label),
//          keys live in the upper 16 KB of the s_kept region (alias analysis:
//          kept-slot s is written at chunk g with s < 64(g+1); key for point p
//          is consumed at chunk p/64 - 1; 16*s >= 16384 + 8*p requires g > 32
//          -> a key is never clobbered before its last read).
// Phase 2: per chunk of 64 (in sorted order):
//   - prefetch next chunk's key + center gather (hidden behind resolve)
//   - diag 64x64 masks via shfl+ballot (registers only)
//   - check chunk points vs ACCUMULATED KEPT LIST: wave s streams kept[s::16]
//     with wave-uniform (broadcast, conflict-free) LDS reads; lane c compares
//     its chunk point in registers. Work = 64 * total_kept, not O(P^2).
//   - barrier; wave 0: ballot/ffs greedy resolve (iters = #kept in chunk),
//     append kept points to the dense list; barrier; wave 1 scatters keep.
// ---------------------------------------------------------------------------
__global__ __launch_bounds__(1024) void nms_fused(
    const float* __restrict__ centers,
    const float* __restrict__ cls_preds,
    const float* __restrict__ class_radius,
    float* __restrict__ out_keep)
{
    __shared__ float4 s_kept[P];            // 32 KB; bytes [16K,32K) alias sort keys
    __shared__ u64 s_rows[64];
    __shared__ u64 s_maskg;
    __shared__ int s_cnt;
    __shared__ unsigned char s_blk[64];
    u64* s_k = (u64*)(&s_kept[P / 2]);

    const int b = blockIdx.x, tid = threadIdx.x;
    const int wv = tid >> 6, lane = tid & 63;
    const float* clsb = cls_preds + (size_t)b * P * 3;
    const float* cenb = centers + (size_t)b * P * 3;

    const float ra = class_radius[0], rbv = class_radius[1], rcv = class_radius[2];
    const float r2a = ra * ra, r2b = rbv * rbv, r2c = rcv * rcv;

    // ---------------- phase 1: sort ----------------
    u64 v[2];
    #pragma unroll
    for (int h = 0; h < 2; ++h) {
        int e = tid + h * 1024;
        float s0 = clsb[e*3], s1 = clsb[e*3+1], s2 = clsb[e*3+2];
        float sc = s0; int lb = 0;
        if (s1 > sc) { sc = s1; lb = 1; }
        if (s2 > sc) { sc = s2; lb = 2; }
        u32 ub = __float_as_uint(sc);
        u32 ord = (ub & 0x80000000u) ? ~ub : (ub | 0x80000000u); // ascending map
        v[h] = ((u64)(~ord) << 32) | (u32)((e << 2) | lb);       // descending
    }
    for (int k = 2; k <= P; k <<= 1) {
        for (int j = k >> 1; j >= 64; j >>= 1) {        // LDS passes
            s_k[tid] = v[0]; s_k[tid + 1024] = v[1];
            __syncthreads();
            #pragma unroll
            for (int h = 0; h < 2; ++h) {
                int e = tid + h * 1024;
                u64 p = s_k[e ^ j];
                bool asc = (e & k) == 0, upper = (e & j) != 0;
                u64 mn = v[h] < p ? v[h] : p, mx = v[h] < p ? p : v[h];
                v[h] = (asc != upper) ? mn : mx;
            }
            __syncthreads();
        }
        int jt = (k >> 1) < 32 ? (k >> 1) : 32;
        for (int j = jt; j >= 1; j >>= 1) {             // shfl passes, no barrier
            #pragma unroll
            for (int h = 0; h < 2; ++h) {
                int e = tid + h * 1024;
                u64 p = shfl_xor_u64(v[h], j);
                bool asc = (e & k) == 0, upper = (e & j) != 0;
                u64 mn = v[h] < p ? v[h] : p, mx = v[h] < p ? p : v[h];
                v[h] = (asc != upper) ? mn : mx;
            }
        }
    }
    s_k[tid] = v[0]; s_k[tid + 1024] = v[1];
    if (tid == 0) s_cnt = 0;
    if (wv == 0) s_blk[lane] = 0;
    __syncthreads();

    // ---------------- phase 2: chunked greedy scan ----------------
    // preload chunk 0 (every wave's lane c holds chunk point c)
    u32 lo = (u32)s_k[lane];
    {
        int o = lo >> 2;
        // fallthrough loads below
    }
    float cx, cy, cz;
    { int o = lo >> 2; cx = cenb[o*3]; cy = cenb[o*3+1]; cz = cenb[o*3+2]; }

    for (int g = 0; g < NCHUNK; ++g) {
        // prefetch next chunk (consumed after the barriers -> latency hidden)
        u32 nlo = 0; float nx = 0.f, ny = 0.f, nz = 0.f;
        if (g + 1 < NCHUNK) {
            nlo = (u32)s_k[(g + 1) * 64 + lane];
            int o = nlo >> 2;
            nx = cenb[o*3]; ny = cenb[o*3+1]; nz = cenb[o*3+2];
        }
        const int lab = lo & 3;
        const float myr2 = lab == 0 ? r2a : (lab == 1 ? r2b : r2c);

        // diag rows via shfl+ballot (suppression symmetric within same class)
        #pragma unroll
        for (int rr = 0; rr < 4; ++rr) {
            int r = (wv << 2) + rr;
            float ox = __shfl(cx, r, 64), oy = __shfl(cy, r, 64), oz = __shfl(cz, r, 64);
            u32 ol = (u32)__shfl((int)lo, r, 64);
            float dx = cx - ox, dy = cy - oy, dz = cz - oz;
            bool sup = (r != lane) && (((ol ^ lo) & 3u) == 0u)
                       && (dx*dx + dy*dy + dz*dz < myr2);
            u64 m = __ballot(sup);
            if (lane == 0) s_rows[r] = m;
        }

        // check this chunk's 64 points vs accumulated kept list
        const int cnt = s_cnt;       // stable: last write fenced by prev barrier
        bool hit = false;
        for (int t = wv; t < cnt; t += 16) {
            float4 e = s_kept[t];    // wave-uniform address -> broadcast, free
            u32 ew = (u32)__float_as_int(e.w);
            float dx = cx - e.x, dy = cy - e.y, dz = cz - e.z;
            if ((((ew ^ lo) & 3u) == 0u) && (dx*dx + dy*dy + dz*dz < myr2)) hit = true;
            if (((t >> 4) & 15) == 15 && __ballot(!hit) == 0ull) break; // all hit
        }
        if (hit) s_blk[lane] = 1;
        __syncthreads();

        // wave 0: greedy resolve + kept-list append
        if (wv == 0) {
            u64 rem = __ballot(s_blk[lane] != 0);
            s_blk[lane] = 0;                      // reset for next chunk
            u64 col = s_rows[lane];               // who I suppress (later bits)
            u64 colmask = (lane == 63) ? 0ull : (~0ull << (lane + 1));
            col &= colmask;
            u64 todo = ~rem;
            u64 keepmask = 0;
            while (todo) {                        // wave-uniform, iters = #kept
                int kk = (int)__ffsll((long long)todo) - 1;
                keepmask |= 1ull << kk;
                u64 ck = shfl_u64(col, kk);
                todo &= ~ck & ~(1ull << kk);
            }
            int c0 = s_cnt;
            if ((keepmask >> lane) & 1ull) {
                int slot = c0 + (int)__popcll(keepmask & ((1ull << lane) - 1ull));
                float4 e; e.x = cx; e.y = cy; e.z = cz;
                e.w = __int_as_float((int)lo);
                s_kept[slot] = e;
            }
            if (lane == 0) {
                s_cnt = c0 + (int)__popcll(keepmask);
                s_maskg = keepmask;
            }
        }
        __syncthreads();

        // wave 1: scatter keep floats for this chunk (reads s_maskg; safe:
        // next overwrite of s_maskg is behind the next chunk's first barrier)
        if (wv == 1) {
            u64 km = s_maskg;
            out_keep[(size_t)b * P + (lo >> 2)] = ((km >> lane) & 1ull) ? 1.0f : 0.0f;
        }

        lo = nlo; cx = nx; cy = ny; cz = nz;
    }
}

// ---------------------------------------------------------------------------
// K2: streaming mask of all outputs (features + centers + cls), full GPU.
// ---------------------------------------------------------------------------
__global__ __launch_bounds__(256) void mask_kernel(
    const float* __restrict__ centers,
    const float* __restrict__ features,
    const float* __restrict__ cls_preds,
    const float* __restrict__ keep,
    float* __restrict__ out_centers,
    float* __restrict__ out_feat,
    float* __restrict__ out_cls)
{
    const int idx = blockIdx.x * 256 + threadIdx.x;
    if (idx < FEAT4) {
        const int row = idx >> 8;                    // C/4 = 256 f4 per row
        const float m = keep[row];
        float4 v = ((const float4*)features)[idx];
        v.x *= m; v.y *= m; v.z *= m; v.w *= m;
        ((float4*)out_feat)[idx] = v;
    } else if (idx < FEAT4 + CEN4) {
        const int q = idx - FEAT4;
        float4 v = ((const float4*)centers)[q];
        const int e = q * 4;
        v.x *= keep[(e    ) / 3]; v.y *= keep[(e + 1) / 3];
        v.z *= keep[(e + 2) / 3]; v.w *= keep[(e + 3) / 3];
        ((float4*)out_centers)[q] = v;
    } else if (idx < FEAT4 + 2 * CEN4) {
        const int q = idx - FEAT4 - CEN4;
        float4 v = ((const float4*)cls_preds)[q];
        const int e = q * 4;
        v.x *= keep[(e    ) / 3]; v.y *= keep[(e + 1) / 3];
        v.z *= keep[(e + 2) / 3]; v.w *= keep[(e + 3) / 3];
        ((float4*)out_cls)[q] = v;
    }
}

extern "C" void kernel_launch(void* const* d_in, const int* in_sizes, int n_in,
                              void* d_out, int out_size, void* d_ws, size_t ws_size,
                              hipStream_t stream) {
    const float* centers      = (const float*)d_in[0];
    const float* features     = (const float*)d_in[1];
    const float* cls_preds    = (const float*)d_in[2];
    const float* class_radius = (const float*)d_in[3];

    float* out = (float*)d_out;
    float* out_centers = out;                                   // B*P*3
    float* out_feat    = out + (size_t)B * P * 3;               // B*P*C
    float* out_cls     = out_feat + (size_t)B * P * C;          // B*P*K
    float* out_keep    = out_cls + (size_t)B * P * 3;           // B*P

    hipLaunchKernelGGL(nms_fused, dim3(B), dim3(1024), 0, stream,
                       centers, cls_preds, class_radius, out_keep);
    hipLaunchKernelGGL(mask_kernel, dim3((FEAT4 + 2 * CEN4 + 255) / 256), dim3(256),
                       0, stream,
                       centers, features, cls_preds, out_keep,
                       out_centers, out_feat, out_cls);
}

// Round 6
// 191.854 us; speedup vs baseline: 2.2927x; 2.2927x over previous
//
#include <hip/hip_runtime.h>

#define B 8
#define P 2048
#define C 1024
#define NCHUNK 32
#define FEAT4 (B*P*C/4)   // 4194304 float4s of features
#define CEN4  (B*P*3/4)   // 12288 float4s of centers (and of cls_preds)

typedef unsigned long long u64;
typedef unsigned int u32;

__device__ __forceinline__ u64 shfl_xor_u64(u64 x, int m) {
    int lo = __shfl_xor((int)(u32)x, m, 64);
    int hi = __shfl_xor((int)(u32)(x >> 32), m, 64);
    return ((u64)(u32)hi << 32) | (u32)lo;
}

// ---------------------------------------------------------------------------
// K1: per-scene sort on packed 64-bit keys (unchanged from R4 -- known good).
// Key = (desc score) << 32 | idx<<2 | label. Emits sorted centers + indices.
// ---------------------------------------------------------------------------
__global__ __launch_bounds__(1024) void sort_kernel(
    const float* __restrict__ centers,
    const float* __restrict__ cls_preds,
    float4* __restrict__ scent,
    int* __restrict__ sidx)
{
    __shared__ u64 s_k[P];
    const int b = blockIdx.x, tid = threadIdx.x;
    const float* clsb = cls_preds + (size_t)b * P * 3;
    const float* cenb = centers + (size_t)b * P * 3;

    u64 v[2];
    #pragma unroll
    for (int h = 0; h < 2; ++h) {
        int e = tid + h * 1024;
        float s0 = clsb[e*3], s1 = clsb[e*3+1], s2 = clsb[e*3+2];
        float sc = s0; int lb = 0;
        if (s1 > sc) { sc = s1; lb = 1; }
        if (s2 > sc) { sc = s2; lb = 2; }
        u32 ub = __float_as_uint(sc);
        u32 ord = (ub & 0x80000000u) ? ~ub : (ub | 0x80000000u);
        v[h] = ((u64)(~ord) << 32) | (u32)((e << 2) | lb);
    }
    for (int k = 2; k <= P; k <<= 1) {
        for (int j = k >> 1; j >= 64; j >>= 1) {
            s_k[tid] = v[0]; s_k[tid + 1024] = v[1];
            __syncthreads();
            #pragma unroll
            for (int h = 0; h < 2; ++h) {
                int e = tid + h * 1024;
                u64 p = s_k[e ^ j];
                bool asc = (e & k) == 0, upper = (e & j) != 0;
                u64 mn = v[h] < p ? v[h] : p, mx = v[h] < p ? p : v[h];
                v[h] = (asc != upper) ? mn : mx;
            }
            __syncthreads();
        }
        int jt = (k >> 1) < 32 ? (k >> 1) : 32;
        for (int j = jt; j >= 1; j >>= 1) {
            #pragma unroll
            for (int h = 0; h < 2; ++h) {
                int e = tid + h * 1024;
                u64 p = shfl_xor_u64(v[h], j);
                bool asc = (e & k) == 0, upper = (e & j) != 0;
                u64 mn = v[h] < p ? v[h] : p, mx = v[h] < p ? p : v[h];
                v[h] = (asc != upper) ? mn : mx;
            }
        }
    }
    s_k[tid] = v[0]; s_k[tid + 1024] = v[1];
    __syncthreads();
    #pragma unroll
    for (int h = 0; h < 2; ++h) {
        int pos = tid + h * 1024;
        u32 lo = (u32)s_k[pos];
        int orig = (int)(lo >> 2);
        float4 c;
        c.x = cenb[orig*3]; c.y = cenb[orig*3+1]; c.z = cenb[orig*3+2];
        c.w = __int_as_float((int)(lo & 3));
        scent[b * P + pos] = c;
        sidx[b * P + pos] = (int)lo;
    }
}

// ---------------------------------------------------------------------------
// K2: FULL suppression rows, word-major. matT[b][w][i] bit u = point j=32w+u
// suppresses sorted point i (same class & dist < r). Symmetric; self-bit set
// (harmless: resolve masks it out, update is idempotent). Block (b,gi) owns
// 64 i's; whole scene's sorted centers staged in LDS (32 KB); inner j-loop is
// wave-uniform -> LDS broadcast, conflict-free. All global accesses coalesced.
// ---------------------------------------------------------------------------
__global__ __launch_bounds__(512) void matrix_kernel(
    const float4* __restrict__ scent,
    const float* __restrict__ class_radius,
    u32* __restrict__ matT)
{
    __shared__ float4 s_cent[P];   // 32 KB
    const int b = blockIdx.x >> 5, gi = blockIdx.x & 31;
    const int tid = threadIdx.x, wv = tid >> 6, lane = tid & 63;

    const float4 cj = scent[(size_t)b * P + (gi << 6) + lane];  // coalesced
    const int labj = __float_as_int(cj.w);
    const float r = class_radius[labj];
    const float r2 = r * r;

    for (int i = tid; i < P; i += 512) s_cent[i] = scent[(size_t)b * P + i];
    __syncthreads();

    for (int w = wv; w < 64; w += 8) {
        u32 acc = 0;
        #pragma unroll
        for (int u = 0; u < 32; ++u) {
            float4 ci = s_cent[(w << 5) + u];        // uniform -> broadcast
            float dx = cj.x - ci.x, dy = cj.y - ci.y, dz = cj.z - ci.z;
            bool sup = (__float_as_int(ci.w) == labj)
                       && (dx*dx + dy*dy + dz*dz < r2);
            acc |= ((u32)sup) << u;
        }
        matT[((size_t)b * 64 + w) * P + (gi << 6) + lane] = acc;  // coalesced
    }
}

// ---------------------------------------------------------------------------
// K3: greedy resolution, one block (9 waves) per scene, ONE barrier/chunk.
//  - waves 1..8: double-buffered prefetch of next chunk's 64x65-padded tile
//    (full rows of its 64 points), coalesced global reads; latency hidden
//    behind wave 0's resolve of the current chunk.
//  - wave 0: rem = removed[2g..2g+1] (2 LDS words); within-chunk greedy by
//    PARALLEL PEELING: keep all alive points with no alive earlier in-chunk
//    suppressor; drop their suppressees; repeat (== sequential greedy;
//    rounds = chain depth, ~2-5). Then scatter keep and incrementally OR the
//    kept points' full rows into removed[64] (ffs over keepmask; padded tile
//    -> conflict-free).
// ---------------------------------------------------------------------------
__global__ __launch_bounds__(576) void scan_kernel(
    const u32* __restrict__ matT,
    const int* __restrict__ sidx,
    float* __restrict__ out_keep)
{
    __shared__ u32 s_tile[2][64][65];   // [buf][q][w], padded: bank (q+w)&31
    __shared__ u32 s_removed[64];
    __shared__ int s_sidx[P];
    const int b = blockIdx.x;
    const int tid = threadIdx.x, wv = tid >> 6, lane = tid & 63;
    const u32* mb = matT + (size_t)b * 64 * P;

    for (int i = tid; i < P; i += 576) s_sidx[i] = sidx[(size_t)b * P + i];
    if (tid < 64) s_removed[tid] = 0;
    if (wv >= 1) {                       // stage chunk 0 into buf 0
        #pragma unroll
        for (int rr = 0; rr < 8; ++rr) {
            int w = ((wv - 1) << 3) + rr;
            s_tile[0][lane][w] = mb[(size_t)w * P + lane];
        }
    }
    __syncthreads();

    for (int g = 0; g < NCHUNK; ++g) {
        const int buf = g & 1;
        if (wv >= 1 && g + 1 < NCHUNK) { // prefetch chunk g+1 into other buf
            const int nb = (g + 1) << 6;
            #pragma unroll
            for (int rr = 0; rr < 8; ++rr) {
                int w = ((wv - 1) << 3) + rr;
                s_tile[buf ^ 1][lane][w] = mb[(size_t)w * P + nb + lane];
            }
        }
        if (wv == 0) {
            const int base = g << 6;
            u64 row = (u64)s_tile[buf][lane][2*g]
                    | ((u64)s_tile[buf][lane][2*g + 1] << 32);
            u64 rem = (u64)s_removed[2*g] | ((u64)s_removed[2*g + 1] << 32);
            u64 alive = ~rem;
            const u64 below = (1ull << lane) - 1ull;
            u64 keepm = 0;
            while (alive) {              // peeling: rounds = chain depth
                bool ok = ((alive >> lane) & 1ull) && ((row & alive & below) == 0ull);
                u64 newk = __ballot(ok);
                keepm |= newk;
                bool dead = (row & newk) != 0ull;
                u64 deadm = __ballot(dead);
                alive &= ~(newk | deadm);
            }
            int orig = s_sidx[base + lane] >> 2;
            out_keep[(size_t)b * P + orig] = ((keepm >> lane) & 1ull) ? 1.0f : 0.0f;
            // incremental removed[] update: lane == word index
            u32 acc = 0;
            u64 m = keepm;
            while (m) {
                int q = (int)__ffsll((long long)m) - 1;
                acc |= s_tile[buf][q][lane];   // banks (q+lane)&31: conflict-free
                m &= m - 1ull;
            }
            s_removed[lane] |= acc;
        }
        __syncthreads();
    }
}

// ---------------------------------------------------------------------------
// K4: streaming mask of all outputs (features + centers + cls), full GPU.
// ---------------------------------------------------------------------------
__global__ __launch_bounds__(256) void mask_kernel(
    const float* __restrict__ centers,
    const float* __restrict__ features,
    const float* __restrict__ cls_preds,
    const float* __restrict__ keep,
    float* __restrict__ out_centers,
    float* __restrict__ out_feat,
    float* __restrict__ out_cls)
{
    const int idx = blockIdx.x * 256 + threadIdx.x;
    if (idx < FEAT4) {
        const int row = idx >> 8;                    // C/4 = 256 f4 per row
        const float m = keep[row];
        float4 v = ((const float4*)features)[idx];
        v.x *= m; v.y *= m; v.z *= m; v.w *= m;
        ((float4*)out_feat)[idx] = v;
    } else if (idx < FEAT4 + CEN4) {
        const int q = idx - FEAT4;
        float4 v = ((const float4*)centers)[q];
        const int e = q * 4;
        v.x *= keep[(e    ) / 3]; v.y *= keep[(e + 1) / 3];
        v.z *= keep[(e + 2) / 3]; v.w *= keep[(e + 3) / 3];
        ((float4*)out_centers)[q] = v;
    } else if (idx < FEAT4 + 2 * CEN4) {
        const int q = idx - FEAT4 - CEN4;
        float4 v = ((const float4*)cls_preds)[q];
        const int e = q * 4;
        v.x *= keep[(e    ) / 3]; v.y *= keep[(e + 1) / 3];
        v.z *= keep[(e + 2) / 3]; v.w *= keep[(e + 3) / 3];
        ((float4*)out_cls)[q] = v;
    }
}

extern "C" void kernel_launch(void* const* d_in, const int* in_sizes, int n_in,
                              void* d_out, int out_size, void* d_ws, size_t ws_size,
                              hipStream_t stream) {
    const float* centers      = (const float*)d_in[0];
    const float* features     = (const float*)d_in[1];
    const float* cls_preds    = (const float*)d_in[2];
    const float* class_radius = (const float*)d_in[3];

    float* out = (float*)d_out;
    float* out_centers = out;                                   // B*P*3
    float* out_feat    = out + (size_t)B * P * 3;               // B*P*C
    float* out_cls     = out_feat + (size_t)B * P * C;          // B*P*K
    float* out_keep    = out_cls + (size_t)B * P * 3;           // B*P

    // scratch inside out_feat (64 MB), fully rewritten by mask_kernel:
    //   matT  : 1,048,576 u32 (4 MB), layout matT[b][w][i]
    //   scent :    16,384 float4
    //   sidx  :    16,384 int
    u32*    matT  = (u32*)out_feat;
    float4* scent = (float4*)(out_feat + 1048576);
    int*    sidx  = (int*)(out_feat + 1048576 + 65536);

    hipLaunchKernelGGL(sort_kernel, dim3(B), dim3(1024), 0, stream,
                       centers, cls_preds, scent, sidx);
    hipLaunchKernelGGL(matrix_kernel, dim3(B * 32), dim3(512), 0, stream,
                       scent, class_radius, matT);
    hipLaunchKernelGGL(scan_kernel, dim3(B), dim3(576), 0, stream,
                       matT, sidx, out_keep);
    hipLaunchKernelGGL(mask_kernel, dim3((FEAT4 + 2 * CEN4 + 255) / 256), dim3(256),
                       0, stream,
                       centers, features, cls_preds, out_keep,
                       out_centers, out_feat, out_cls);
}

// Round 7
// 180.121 us; speedup vs baseline: 2.4420x; 1.0651x over previous
//
#include <hip/hip_runtime.h>

#define B 8
#define P 2048
#define C 1024
#define NCHUNK 32
#define FEAT4 (B*P*C/4)   // 4194304 float4s of features
#define CEN4  (B*P*3/4)   // 12288 float4s of centers (and of cls_preds)

typedef unsigned long long u64;
typedef unsigned int u32;

// ---------------------------------------------------------------------------
// K1: full-GPU rank sort. Keys unique (idx packed in low bits) =>
// rank(p) = #{k : key[k] < key[p]} is a bijection onto [0,P).
// Block (b,gi) ranks sorted-destination for its 64 points: all 2048 scene
// keys computed into LDS (4/thread), wave wv counts slice [wv*256, wv*256+256)
// for all 64 targets via wave-uniform broadcast reads; LDS-reduce; wave 0
// gathers centers and scatters scent[rank] / sidx[rank].
// Key = (~ord(score))<<32 | idx<<2 | label: ascending u64 == descending
// score, ties -> smaller original index (jnp.argmax greedy semantics).
// ---------------------------------------------------------------------------
__global__ __launch_bounds__(512) void rank_kernel(
    const float* __restrict__ centers,
    const float* __restrict__ cls_preds,
    float4* __restrict__ scent,
    int* __restrict__ sidx)
{
    __shared__ u64 s_keys[P];       // 16 KB
    __shared__ u32 s_cnt[64][9];    // padded reduce buffer
    const int b = blockIdx.x >> 5, gi = blockIdx.x & 31;
    const int tid = threadIdx.x, wv = tid >> 6, lane = tid & 63;
    const float* clsb = cls_preds + (size_t)b * P * 3;
    const float* cenb = centers + (size_t)b * P * 3;

    for (int e = tid; e < P; e += 512) {
        float s0 = clsb[e*3], s1 = clsb[e*3+1], s2 = clsb[e*3+2];
        float sc = s0; int lb = 0;
        if (s1 > sc) { sc = s1; lb = 1; }
        if (s2 > sc) { sc = s2; lb = 2; }
        u32 ub = __float_as_uint(sc);
        u32 ord = (ub & 0x80000000u) ? ~ub : (ub | 0x80000000u);
        s_keys[e] = ((u64)(~ord) << 32) | (u32)((e << 2) | lb);
    }
    __syncthreads();

    const u64 myk = s_keys[(gi << 6) + lane];
    u32 c = 0;
    const int sbase = wv << 8;
    #pragma unroll 8
    for (int u = 0; u < 256; ++u)            // wave-uniform -> broadcast, free
        c += (s_keys[sbase + u] < myk) ? 1u : 0u;
    s_cnt[lane][wv] = c;
    __syncthreads();

    if (wv == 0) {
        u32 rank = 0;
        #pragma unroll
        for (int s = 0; s < 8; ++s) rank += s_cnt[lane][s];
        u32 lo = (u32)myk;
        int orig = (int)(lo >> 2);
        float4 cc;
        cc.x = cenb[orig*3]; cc.y = cenb[orig*3+1]; cc.z = cenb[orig*3+2];
        cc.w = __int_as_float((int)(lo & 3));
        scent[(size_t)b * P + rank] = cc;
        sidx[(size_t)b * P + rank] = (int)lo;
    }
}

// ---------------------------------------------------------------------------
// K2: FULL suppression rows, word-major. matT[b][w][i] bit u = point j=32w+u
// suppresses sorted point i (same class & dist < r). Symmetric; self-bit set
// (harmless: resolve masks it, update idempotent). Block (b,gi) owns 64 i's;
// scene's sorted centers staged in LDS; inner j-loop wave-uniform broadcast.
// ---------------------------------------------------------------------------
__global__ __launch_bounds__(512) void matrix_kernel(
    const float4* __restrict__ scent,
    const float* __restrict__ class_radius,
    u32* __restrict__ matT)
{
    __shared__ float4 s_cent[P];   // 32 KB
    const int b = blockIdx.x >> 5, gi = blockIdx.x & 31;
    const int tid = threadIdx.x, wv = tid >> 6, lane = tid & 63;

    const float4 cj = scent[(size_t)b * P + (gi << 6) + lane];  // coalesced
    const int labj = __float_as_int(cj.w);
    const float r = class_radius[labj];
    const float r2 = r * r;

    for (int i = tid; i < P; i += 512) s_cent[i] = scent[(size_t)b * P + i];
    __syncthreads();

    for (int w = wv; w < 64; w += 8) {
        u32 acc = 0;
        #pragma unroll
        for (int u = 0; u < 32; ++u) {
            float4 ci = s_cent[(w << 5) + u];        // uniform -> broadcast
            float dx = cj.x - ci.x, dy = cj.y - ci.y, dz = cj.z - ci.z;
            bool sup = (__float_as_int(ci.w) == labj)
                       && (dx*dx + dy*dy + dz*dz < r2);
            acc |= ((u32)sup) << u;
        }
        matT[((size_t)b * 64 + w) * P + (gi << 6) + lane] = acc;  // coalesced
    }
}

// ---------------------------------------------------------------------------
// K3: greedy resolution, one block (9 waves) per scene, ONE barrier/chunk.
// Waves 1..8 double-buffer-prefetch next chunk's padded row tile; wave 0:
// parallel-peeling resolve (== sequential greedy; rounds = chain depth),
// scatter keep, incremental removed[] OR-update (lane == word index).
// ---------------------------------------------------------------------------
__global__ __launch_bounds__(576) void scan_kernel(
    const u32* __restrict__ matT,
    const int* __restrict__ sidx,
    float* __restrict__ out_keep)
{
    __shared__ u32 s_tile[2][64][65];   // [buf][q][w], padded: bank (q+w)&31
    __shared__ u32 s_removed[64];
    __shared__ int s_sidx[P];
    const int b = blockIdx.x;
    const int tid = threadIdx.x, wv = tid >> 6, lane = tid & 63;
    const u32* mb = matT + (size_t)b * 64 * P;

    for (int i = tid; i < P; i += 576) s_sidx[i] = sidx[(size_t)b * P + i];
    if (tid < 64) s_removed[tid] = 0;
    if (wv >= 1) {                       // stage chunk 0 into buf 0
        #pragma unroll
        for (int rr = 0; rr < 8; ++rr) {
            int w = ((wv - 1) << 3) + rr;
            s_tile[0][lane][w] = mb[(size_t)w * P + lane];
        }
    }
    __syncthreads();

    for (int g = 0; g < NCHUNK; ++g) {
        const int buf = g & 1;
        if (wv >= 1 && g + 1 < NCHUNK) { // prefetch chunk g+1 into other buf
            const int nb = (g + 1) << 6;
            #pragma unroll
            for (int rr = 0; rr < 8; ++rr) {
                int w = ((wv - 1) << 3) + rr;
                s_tile[buf ^ 1][lane][w] = mb[(size_t)w * P + nb + lane];
            }
        }
        if (wv == 0) {
            const int base = g << 6;
            u64 row = (u64)s_tile[buf][lane][2*g]
                    | ((u64)s_tile[buf][lane][2*g + 1] << 32);
            u64 rem = (u64)s_removed[2*g] | ((u64)s_removed[2*g + 1] << 32);
            u64 alive = ~rem;
            const u64 below = (1ull << lane) - 1ull;
            u64 keepm = 0;
            while (alive) {              // peeling: rounds = chain depth
                bool ok = ((alive >> lane) & 1ull) && ((row & alive & below) == 0ull);
                u64 newk = __ballot(ok);
                keepm |= newk;
                bool dead = (row & newk) != 0ull;
                u64 deadm = __ballot(dead);
                alive &= ~(newk | deadm);
            }
            int orig = s_sidx[base + lane] >> 2;
            out_keep[(size_t)b * P + orig] = ((keepm >> lane) & 1ull) ? 1.0f : 0.0f;
            // incremental removed[] update: lane == word index
            u32 acc = 0;
            u64 m = keepm;
            while (m) {
                int q = (int)__ffsll((long long)m) - 1;
                acc |= s_tile[buf][q][lane];   // banks (q+lane)&31: conflict-free
                m &= m - 1ull;
            }
            s_removed[lane] |= acc;
        }
        __syncthreads();
    }
}

// ---------------------------------------------------------------------------
// K4: streaming mask of all outputs (features + centers + cls), full GPU.
// ---------------------------------------------------------------------------
__global__ __launch_bounds__(256) void mask_kernel(
    const float* __restrict__ centers,
    const float* __restrict__ features,
    const float* __restrict__ cls_preds,
    const float* __restrict__ keep,
    float* __restrict__ out_centers,
    float* __restrict__ out_feat,
    float* __restrict__ out_cls)
{
    const int idx = blockIdx.x * 256 + threadIdx.x;
    if (idx < FEAT4) {
        const int row = idx >> 8;                    // C/4 = 256 f4 per row
        const float m = keep[row];
        float4 v = ((const float4*)features)[idx];
        v.x *= m; v.y *= m; v.z *= m; v.w *= m;
        ((float4*)out_feat)[idx] = v;
    } else if (idx < FEAT4 + CEN4) {
        const int q = idx - FEAT4;
        float4 v = ((const float4*)centers)[q];
        const int e = q * 4;
        v.x *= keep[(e    ) / 3]; v.y *= keep[(e + 1) / 3];
        v.z *= keep[(e + 2) / 3]; v.w *= keep[(e + 3) / 3];
        ((float4*)out_centers)[q] = v;
    } else if (idx < FEAT4 + 2 * CEN4) {
        const int q = idx - FEAT4 - CEN4;
        float4 v = ((const float4*)cls_preds)[q];
        const int e = q * 4;
        v.x *= keep[(e    ) / 3]; v.y *= keep[(e + 1) / 3];
        v.z *= keep[(e + 2) / 3]; v.w *= keep[(e + 3) / 3];
        ((float4*)out_cls)[q] = v;
    }
}

extern "C" void kernel_launch(void* const* d_in, const int* in_sizes, int n_in,
                              void* d_out, int out_size, void* d_ws, size_t ws_size,
                              hipStream_t stream) {
    const float* centers      = (const float*)d_in[0];
    const float* features     = (const float*)d_in[1];
    const float* cls_preds    = (const float*)d_in[2];
    const float* class_radius = (const float*)d_in[3];

    float* out = (float*)d_out;
    float* out_centers = out;                                   // B*P*3
    float* out_feat    = out + (size_t)B * P * 3;               // B*P*C
    float* out_cls     = out_feat + (size_t)B * P * C;          // B*P*K
    float* out_keep    = out_cls + (size_t)B * P * 3;           // B*P

    // scratch inside out_feat (64 MB), fully rewritten by mask_kernel:
    //   matT  : 1,048,576 u32 (4 MB), layout matT[b][w][i]
    //   scent :    16,384 float4
    //   sidx  :    16,384 int
    u32*    matT  = (u32*)out_feat;
    float4* scent = (float4*)(out_feat + 1048576);
    int*    sidx  = (int*)(out_feat + 1048576 + 65536);

    hipLaunchKernelGGL(rank_kernel, dim3(B * 32), dim3(512), 0, stream,
                       centers, cls_preds, scent, sidx);
    hipLaunchKernelGGL(matrix_kernel, dim3(B * 32), dim3(512), 0, stream,
                       scent, class_radius, matT);
    hipLaunchKernelGGL(scan_kernel, dim3(B), dim3(576), 0, stream,
                       matT, sidx, out_keep);
    hipLaunchKernelGGL(mask_kernel, dim3((FEAT4 + 2 * CEN4 + 255) / 256), dim3(256),
                       0, stream,
                       centers, features, cls_preds, out_keep,
                       out_centers, out_feat, out_cls);
}